// Round 5
// baseline (199.620 us; speedup 1.0000x reference)
//
#include <hip/hip_runtime.h>
#include <math.h>

typedef _Float16 half8 __attribute__((ext_vector_type(8)));
typedef float    f32x4 __attribute__((ext_vector_type(4)));

#define DIM     128
#define NCODES  1024
#define M_ROWS  (32*64*64)   // 131072
#define MTILE   256          // rows per block in phase 1 (4 waves x 64 rows)
#define NCHUNK  64           // codes per LDS chunk in phase 1
#define M_TEST  3.0e-3f      // flag margin (quantized-score gap)
#define WL_CAP  16384
#define GR      64           // flagged rows per vq_exact block
#define CSTR    132          // f32 LDS stride (528 B, 16B aligned; worst alias 2-way = free)

// fl32(v*v), immune to FMA contraction (f64 product exact, one rounding).
__device__ __forceinline__ float sqf(float v) {
    return (float)((double)v * (double)v);
}

// ---------------------------------------------------------------------------
// Prep: blocks 0..511 transpose cb->cbT (f32) and ch (fp16), one elem/thread.
// Blocks 512..515: cc[n] = np axis-0 sequential sum of rounded squares.
// Blocks 516..579: init bst[] (per-flagged-row best key) to all-ones.
// ---------------------------------------------------------------------------
__global__ void vq_prep(const float* __restrict__ cb,
                        float* __restrict__ cbT,
                        _Float16* __restrict__ ch,
                        float* __restrict__ cc,
                        int* __restrict__ cnt,
                        unsigned long long* __restrict__ bst) {
    const int b = blockIdx.x;
    if (b < 512) {
        int e = b * 256 + threadIdx.x;      // 0..131071
        int n = e & 1023, k = e >> 10;
        float v = cb[k * NCODES + n];       // coalesced in n
        cbT[n * DIM + k] = v;
        ch[n * DIM + k]  = (_Float16)v;
    } else if (b < 516) {
        int n = (b - 512) * 256 + threadIdx.x;   // 0..1023
        float acc = 0.f;
        for (int k = 0; k < DIM; ++k)
            acc = acc + sqf(cb[k * NCODES + n]); // np axis-0 order
        cc[n] = acc;
        if (n == 0) *cnt = 0;
    } else {
        int s = (b - 516) * 256 + threadIdx.x;   // 0..16383
        bst[s] = 0xFFFFFFFFFFFFFFFFull;
    }
}

// ---------------------------------------------------------------------------
// Phase 1 v5: fp16 MFMA scoring, fused top-2 argmin.
//  LDS-pipe analysis (round-4 counters): B-chunk re-read per wave is the
//  saturated resource (~80% LDS busy; conflicts are a fixed 4cyc/1KB-read in
//  every layout). Fix: 4 m-frags per wave (64 rows) -> 0.25 ds_reads/MFMA
//  (was 0.5), halving LDS traffic, combined with round-3's proven dbuf DMA.
//  512 blocks x 256 threads (4 waves x 64 rows), 2 blocks/CU.
// Per-(row,code) arithmetic bit-identical (same fp16 inputs, MFMA k-order,
// score formula incl. +4.0f rounding, pack, top-2 order).
// ---------------------------------------------------------------------------
__device__ __forceinline__ void stage_chunk(const _Float16* __restrict__ ch,
                                            _Float16* lds,
                                            int chunk, int w, int quad, int lane15) {
#pragma unroll
    for (int i = 0; i < 4; ++i) {
        int r = (w << 4) + (i << 2) + quad;          // code row 0..63 of chunk
        // linear LDS dest: uniform half-offset w*2048 + i*512; HW adds
        // lane*16B = quad*128 + lane15*8 halves -> row r at halves r*128.
        const _Float16* g = ch + (size_t)(chunk * NCHUNK + r) * DIM
                               + ((lane15 ^ (r & 7)) << 3);
        __builtin_amdgcn_global_load_lds(
            (const __attribute__((address_space(1))) void*)g,
            (__attribute__((address_space(3))) void*)(lds + (w << 11) + (i << 9)),
            16, 0, 0);
    }
}

__global__ __launch_bounds__(256, 2) void vq_gemm(const float* __restrict__ x,
                                                  const _Float16* __restrict__ ch,
                                                  const float* __restrict__ cc,
                                                  int* __restrict__ idx,
                                                  int* __restrict__ cnt,
                                                  int* __restrict__ wl) {
    __shared__ _Float16 bs[2][NCHUNK * DIM];   // 2 x 16 KB double buffer
    __shared__ float ccL[NCODES];              // 4 KB, packed [c][lane15][j]

    const int t      = threadIdx.x;
    const int w      = t >> 6;
    const int L      = t & 63;
    const int lane15 = L & 15;
    const int quad   = L >> 4;
    const int rowbase = blockIdx.x * MTILE + w * 64;

    stage_chunk(ch, bs[0], 0, w, quad, lane15);

    // cc+4 into LDS once, float4-packed: ccL[(c*16+l)*4+j] = cc[c*64+j*16+l]+4.
#pragma unroll
    for (int i = 0; i < 4; ++i) {
        int e = t + 256 * i;            // 0..1023 (dest index)
        int c = e >> 6, rem = e & 63;
        int l = rem >> 2, j = rem & 3;
        ccL[e] = cc[c * 64 + j * 16 + l] + 4.0f;
    }

    // A fragments from global x (f32 -> fp16), persistent across chunks.
    half8 af[4][4];
#pragma unroll
    for (int m = 0; m < 4; ++m) {
#pragma unroll
        for (int ks = 0; ks < 4; ++ks) {
            const float* src = x + (size_t)(rowbase + m * 16 + lane15) * DIM
                                 + ks * 32 + quad * 8;
            float4 f0 = *(const float4*)src;
            float4 f1 = *(const float4*)(src + 4);
            half8 h;
            h[0] = (_Float16)f0.x; h[1] = (_Float16)f0.y;
            h[2] = (_Float16)f0.z; h[3] = (_Float16)f0.w;
            h[4] = (_Float16)f1.x; h[5] = (_Float16)f1.y;
            h[6] = (_Float16)f1.z; h[7] = (_Float16)f1.w;
            af[m][ks] = h;
        }
    }

    int roff[4];
#pragma unroll
    for (int ks = 0; ks < 4; ++ks)
        roff[ks] = lane15 * DIM + ((((ks << 2) + quad) ^ (lane15 & 7)) << 3);

    unsigned p1[4][4], p2[4][4];
#pragma unroll
    for (int m = 0; m < 4; ++m)
#pragma unroll
        for (int r = 0; r < 4; ++r) { p1[m][r] = 0xFFFFFFFFu; p2[m][r] = 0xFFFFFFFFu; }

    __syncthreads();   // chunk-0 DMA + ccL writes resident

    for (int c = 0; c < NCODES / NCHUNK; ++c) {
        if (c + 1 < NCODES / NCHUNK)
            stage_chunk(ch, bs[(c + 1) & 1], c + 1, w, quad, lane15);   // async

        float4 ccv = *(const float4*)&ccL[((c << 4) + lane15) << 2];
        float cc4[4] = {ccv.x, ccv.y, ccv.z, ccv.w};

        const _Float16* bp = bs[c & 1];
        f32x4 acc[4][4];
#pragma unroll
        for (int m = 0; m < 4; ++m)
#pragma unroll
            for (int j = 0; j < 4; ++j) {
                f32x4 z = {0.f, 0.f, 0.f, 0.f};
                acc[m][j] = z;
            }

#pragma unroll
        for (int ks = 0; ks < 4; ++ks) {
            half8 bf[4];
#pragma unroll
            for (int j = 0; j < 4; ++j)
                bf[j] = *(const half8*)(bp + (j << 11) + roff[ks]);
#pragma unroll
            for (int j = 0; j < 4; ++j)
#pragma unroll
                for (int m = 0; m < 4; ++m)
                    acc[m][j] = __builtin_amdgcn_mfma_f32_16x16x32_f16(af[m][ks], bf[j], acc[m][j], 0, 0, 0);
        }

#pragma unroll
        for (int j = 0; j < 4; ++j) {
            int col = c * NCHUNK + j * 16 + lane15;
#pragma unroll
            for (int m = 0; m < 4; ++m)
#pragma unroll
                for (int r = 0; r < 4; ++r) {
                    float s = fmaf(-2.0f, acc[m][j][r], cc4[j]);
                    s = fmaxf(s, 0.25f);
                    unsigned up = (__float_as_uint(s) & 0xFFFFFC00u) | (unsigned)col;
                    unsigned a  = p1[m][r];
                    unsigned lo = a < up ? a : up;
                    unsigned hi = a < up ? up : a;
                    p1[m][r] = lo;
                    p2[m][r] = p2[m][r] < hi ? p2[m][r] : hi;
                }
        }
        __syncthreads();   // readers done; DMA c+1 drained (already landed)
    }

    // Cross-lane top-2 merge over the 16 col-lanes.
#pragma unroll
    for (int m = 0; m < 4; ++m)
#pragma unroll
        for (int r = 0; r < 4; ++r) {
            unsigned a1 = p1[m][r], a2 = p2[m][r];
#pragma unroll
            for (int mask = 1; mask <= 8; mask <<= 1) {
                unsigned b1 = (unsigned)__shfl_xor((int)a1, mask, 64);
                unsigned b2 = (unsigned)__shfl_xor((int)a2, mask, 64);
                unsigned n1 = a1 < b1 ? a1 : b1;
                unsigned hi = a1 < b1 ? b1 : a1;
                unsigned mn = a2 < b2 ? a2 : b2;
                unsigned n2 = hi < mn ? hi : mn;
                a1 = n1; a2 = n2;
            }
            if (lane15 == 0) {
                int row = rowbase + m * 16 + quad * 4 + r;
                idx[row] = (int)(a1 & 0x3FFu);
                float s1 = __uint_as_float(a1 & 0xFFFFFC00u);
                float s2 = __uint_as_float(a2 & 0xFFFFFC00u);
                if (s2 - s1 < M_TEST) {
                    int slot = atomicAdd(cnt, 1);
                    if (slot < WL_CAP) wl[slot] = row;
                }
            }
        }
}

// ---------------------------------------------------------------------------
// Phase 2 v3: np-exact rescoring (unchanged).
// Block item = 64 flagged rows x 256 codes; thread tile 4x4; atomicMin merge.
// ---------------------------------------------------------------------------
__global__ __launch_bounds__(256, 2) void vq_exact(const float* __restrict__ x,
                                                   const float* __restrict__ cbT,
                                                   const float* __restrict__ cc,
                                                   const int* __restrict__ cnt,
                                                   const int* __restrict__ wl,
                                                   unsigned long long* __restrict__ bst) {
    __shared__ float xsS[GR * CSTR];     // 64 staged x-rows
    __shared__ float cbS[64 * CSTR];     // 64-code chunk
    __shared__ float xxS[GR];

    const int t  = threadIdx.x;
    const int r4 = t >> 4;      // row group 0..15 (rows 4*r4 .. 4*r4+3)
    const int q  = t & 15;      // code residue 0..15

    int count = *cnt;
    if (count > WL_CAP) count = WL_CAP;
    const int ngrp   = (count + GR - 1) / GR;
    const int nitems = ngrp * 4;

    for (int it = blockIdx.x; it < nitems; it += gridDim.x) {
        const int grp = it >> 2;        // row group (consecutive blocks share rows)
        const int cq  = it & 3;         // code quarter

        __syncthreads();   // previous item's xsS readers done
#pragma unroll
        for (int j = 0; j < 8; ++j) {
            int e  = t + 256 * j;       // float4 index 0..2047
            int rr = e >> 5, k4 = e & 31;
            int sl = grp * GR + rr;
            sl = sl < count ? sl : count - 1;   // clamp: dup rows benign (guarded at merge)
            int rw = wl[sl];
            float4 v = ((const float4*)x)[(size_t)rw * 32 + k4];
            *(float4*)&xsS[rr * CSTR + k4 * 4] = v;
        }
        __syncthreads();

        // xx once per row: numpy pairwise sum, n=128 block, 8 accumulators
        // (verified form), computed by wave 0 (one thread per row).
        if (t < GR) {
            const float* xs = &xsS[t * CSTR];
            float r0 = sqf(xs[0]), r1 = sqf(xs[1]), r2 = sqf(xs[2]), r3 = sqf(xs[3]);
            float r4_ = sqf(xs[4]), r5 = sqf(xs[5]), r6 = sqf(xs[6]), r7 = sqf(xs[7]);
#pragma unroll
            for (int k = 8; k < DIM; k += 8) {
                r0 = r0 + sqf(xs[k + 0]); r1 = r1 + sqf(xs[k + 1]);
                r2 = r2 + sqf(xs[k + 2]); r3 = r3 + sqf(xs[k + 3]);
                r4_ = r4_ + sqf(xs[k + 4]); r5 = r5 + sqf(xs[k + 5]);
                r6 = r6 + sqf(xs[k + 6]); r7 = r7 + sqf(xs[k + 7]);
            }
            xxS[t] = ((r0 + r1) + (r2 + r3)) + ((r4_ + r5) + (r6 + r7));
        }
        __syncthreads();

        float xxv[4];
#pragma unroll
        for (int i = 0; i < 4; ++i) xxv[i] = xxS[r4 * 4 + i];

        unsigned long long best[4];
#pragma unroll
        for (int i = 0; i < 4; ++i) best[i] = 0xFFFFFFFFFFFFFFFFull;

        for (int ch = 0; ch < 4; ++ch) {
            const int nb = cq * 256 + ch * 64;      // global code base of chunk
            __syncthreads();   // previous chunk's cbS readers done
#pragma unroll
            for (int j = 0; j < 8; ++j) {
                int e  = t + 256 * j;               // float4 index 0..2047
                int ci = e >> 5, k4 = e & 31;
                float4 v = ((const float4*)cbT)[(size_t)(nb + ci) * 32 + k4];
                *(float4*)&cbS[ci * CSTR + k4 * 4] = v;
            }
            __syncthreads();

            float a[4][4];
#pragma unroll
            for (int i = 0; i < 4; ++i)
#pragma unroll
                for (int j = 0; j < 4; ++j) a[i][j] = 0.f;

#pragma unroll 4
            for (int k4 = 0; k4 < 32; ++k4) {
                float4 xv[4], cv[4];
#pragma unroll
                for (int i = 0; i < 4; ++i)
                    xv[i] = *(const float4*)&xsS[(r4 * 4 + i) * CSTR + k4 * 4];
#pragma unroll
                for (int j = 0; j < 4; ++j)
                    cv[j] = *(const float4*)&cbS[(q + 16 * j) * CSTR + k4 * 4];
#pragma unroll
                for (int i = 0; i < 4; ++i)
#pragma unroll
                    for (int j = 0; j < 4; ++j) {
                        float acc = a[i][j];
                        acc = fmaf(cv[j].x, xv[i].x, acc);
                        acc = fmaf(cv[j].y, xv[i].y, acc);
                        acc = fmaf(cv[j].z, xv[i].z, acc);
                        acc = fmaf(cv[j].w, xv[i].w, acc);
                        a[i][j] = acc;
                    }
            }

#pragma unroll
            for (int j = 0; j < 4; ++j) {
                int n = nb + q + 16 * j;
                float ccn = cc[n];
#pragma unroll
                for (int i = 0; i < 4; ++i) {
                    float tt = xxv[i] + ccn;
                    float d  = tt - (a[i][j] + a[i][j]);
                    unsigned u  = __float_as_uint(d);
                    unsigned mk = (unsigned)(((int)u) >> 31);
                    unsigned f  = u ^ (mk | 0x80000000u);
                    unsigned long long key = ((unsigned long long)f << 32) | (unsigned)n;
                    best[i] = key < best[i] ? key : best[i];
                }
            }
        }

#pragma unroll
        for (int i = 0; i < 4; ++i) {
            unsigned long long b = best[i];
#pragma unroll
            for (int mask = 1; mask <= 8; mask <<= 1) {
                unsigned long long o =
                    (unsigned long long)__shfl_xor((long long)b, mask, 64);
                b = o < b ? o : b;
            }
            if (q == 0) {
                int sl = grp * GR + r4 * 4 + i;
                if (sl < count) atomicMin(&bst[sl], b);
            }
        }
    }
}

// ---------------------------------------------------------------------------
// Phase 2b: write merged winners into idx.
// ---------------------------------------------------------------------------
__global__ void vq_fix(const int* __restrict__ cnt,
                       const int* __restrict__ wl,
                       const unsigned long long* __restrict__ bst,
                       int* __restrict__ idx) {
    int count = *cnt;
    if (count > WL_CAP) count = WL_CAP;
    for (int s = blockIdx.x * 256 + threadIdx.x; s < count; s += gridDim.x * 256)
        idx[wl[s]] = (int)(bst[s] & 0xFFFFFFFFull);
}

// ---------------------------------------------------------------------------
// Phase 3: out = q (codebook column idx[row]); |q - (x + fl(q-x))| <= 4e-7,
// well under the 1e-3 threshold, and skips the 64 MB x read.
// ---------------------------------------------------------------------------
__global__ void vq_out(const float* __restrict__ cbT,
                       const int* __restrict__ idx,
                       float* __restrict__ out) {
    size_t e = (size_t)blockIdx.x * 256 + threadIdx.x;   // float4 index
    int row = (int)(e >> 5);
    int k4  = (int)(e & 31);
    ((float4*)out)[e] = ((const float4*)cbT)[(size_t)idx[row] * 32 + k4];
}

// ---------------------------------------------------------------------------
extern "C" void kernel_launch(void* const* d_in, const int* in_sizes, int n_in,
                              void* d_out, int out_size, void* d_ws, size_t ws_size,
                              hipStream_t stream) {
    const float* x  = (const float*)d_in[0];   // [131072,128] f32
    const float* cb = (const float*)d_in[1];   // [128,1024] f32
    float* out = (float*)d_out;

    char* p = (char*)d_ws;
    float*    cbT = (float*)p;               p += NCODES * DIM * sizeof(float);
    _Float16* ch  = (_Float16*)p;            p += NCODES * DIM * sizeof(_Float16);
    float*    cc  = (float*)p;               p += NCODES * sizeof(float);
    int*      idx = (int*)p;                 p += M_ROWS * sizeof(int);
    int*      cnt = (int*)p;                 p += 16 * sizeof(int);
    int*      wl  = (int*)p;                 p += WL_CAP * sizeof(int);
    unsigned long long* bst = (unsigned long long*)p;

    vq_prep<<<580, 256, 0, stream>>>(cb, cbT, ch, cc, cnt, bst);
    vq_gemm<<<M_ROWS / MTILE, 256, 0, stream>>>(x, ch, cc, idx, cnt, wl);
    vq_exact<<<512, 256, 0, stream>>>(x, cbT, cc, cnt, wl, bst);
    vq_fix<<<64, 256, 0, stream>>>(cnt, wl, bst, idx);
    vq_out<<<(M_ROWS * (DIM / 4)) / 256, 256, 0, stream>>>(cbT, idx, out);
}

// Round 6
// 196.099 us; speedup vs baseline: 1.0180x; 1.0180x over previous
//
#include <hip/hip_runtime.h>
#include <math.h>

typedef _Float16 half8 __attribute__((ext_vector_type(8)));
typedef float    f32x4 __attribute__((ext_vector_type(4)));

#define DIM     128
#define NCODES  1024
#define M_ROWS  (32*64*64)   // 131072
#define MTILE   128          // rows per block in phase 1 (4 waves x 32 rows)
#define NCHUNK  64           // codes per LDS chunk in phase 1
#define M_TEST  3.0e-3f      // flag margin (quantized-score gap)
#define WL_CAP  16384
#define GR      64           // flagged rows per vq_exact block
#define CSTR    132          // f32 LDS stride (528 B, 16B aligned; worst alias 2-way = free)

// fl32(v*v), immune to FMA contraction (f64 product exact, one rounding).
__device__ __forceinline__ float sqf(float v) {
    return (float)((double)v * (double)v);
}

// ---------------------------------------------------------------------------
// Prep: blocks 0..511 transpose cb->cbT (f32) and ch (fp16), one elem/thread.
// Blocks 512..515: cc[n] = np axis-0 sequential sum of rounded squares.
// Blocks 516..579: init bst[] (per-flagged-row best key) to all-ones.
// ---------------------------------------------------------------------------
__global__ void vq_prep(const float* __restrict__ cb,
                        float* __restrict__ cbT,
                        _Float16* __restrict__ ch,
                        float* __restrict__ cc,
                        int* __restrict__ cnt,
                        unsigned long long* __restrict__ bst) {
    const int b = blockIdx.x;
    if (b < 512) {
        int e = b * 256 + threadIdx.x;      // 0..131071
        int n = e & 1023, k = e >> 10;
        float v = cb[k * NCODES + n];       // coalesced in n
        cbT[n * DIM + k] = v;
        ch[n * DIM + k]  = (_Float16)v;
    } else if (b < 516) {
        int n = (b - 512) * 256 + threadIdx.x;   // 0..1023
        float acc = 0.f;
        for (int k = 0; k < DIM; ++k)
            acc = acc + sqf(cb[k * NCODES + n]); // np axis-0 order
        cc[n] = acc;
        if (n == 0) *cnt = 0;
    } else {
        int s = (b - 516) * 256 + threadIdx.x;   // 0..16383
        bst[s] = 0xFFFFFFFFFFFFFFFFull;
    }
}

// ---------------------------------------------------------------------------
// Phase 1 v6: fp16 MFMA scoring, fused top-2 argmin, PIPELINED EPILOGUE.
//  r3 geometry (1024 blocks x 4 waves x 32 rows, dbuf DMA staging) — best
//  measured — plus: two accumulator banks (accA/accB static ping-pong), the
//  top-2 epilogue of chunk c-1 (register-only VALU) runs inside the same
//  barrier interval as the MFMA chain of chunk c, so the scheduler fills
//  MFMA latency with epilogue VALU (r5 showed within-wave serialization of
//  {MFMA-chain -> wait -> epilogue} is the stall, not LDS or residency).
// Per-(row,code) arithmetic bit-identical (same fp16 inputs, MFMA k-order,
// score formula incl. +4.0f rounding, pack, top-2 update order per code).
// ---------------------------------------------------------------------------
__device__ __forceinline__ void stage_chunk(const _Float16* __restrict__ ch,
                                            _Float16* lds,
                                            int chunk, int w, int quad, int lane15) {
#pragma unroll
    for (int i = 0; i < 4; ++i) {
        int r = (w << 4) + (i << 2) + quad;          // code row 0..63 of chunk
        const _Float16* g = ch + (size_t)(chunk * NCHUNK + r) * DIM
                               + ((lane15 ^ (r & 7)) << 3);
        __builtin_amdgcn_global_load_lds(
            (const __attribute__((address_space(1))) void*)g,
            (__attribute__((address_space(3))) void*)(lds + (w << 11) + (i << 9)),
            16, 0, 0);
    }
}

#define ZACC(A)                                                               \
    _Pragma("unroll")                                                         \
    for (int m_ = 0; m_ < 2; ++m_)                                            \
        _Pragma("unroll")                                                     \
        for (int j_ = 0; j_ < 4; ++j_) {                                      \
            f32x4 z_ = {0.f, 0.f, 0.f, 0.f};                                  \
            A[m_][j_] = z_;                                                   \
        }

#define CHAIN(BP, A)                                                          \
    _Pragma("unroll")                                                         \
    for (int ks_ = 0; ks_ < 4; ++ks_) {                                       \
        half8 bf_[4];                                                         \
        _Pragma("unroll")                                                     \
        for (int j_ = 0; j_ < 4; ++j_)                                        \
            bf_[j_] = *(const half8*)((BP) + (j_ << 11) + roff[ks_]);         \
        _Pragma("unroll")                                                     \
        for (int j_ = 0; j_ < 4; ++j_)                                        \
            _Pragma("unroll")                                                 \
            for (int m_ = 0; m_ < 2; ++m_)                                    \
                A[m_][j_] = __builtin_amdgcn_mfma_f32_16x16x32_f16(           \
                    af[m_][ks_], bf_[j_], A[m_][j_], 0, 0, 0);                \
    }

#define EPI(A, CB, CC4)                                                       \
    _Pragma("unroll")                                                         \
    for (int j_ = 0; j_ < 4; ++j_) {                                          \
        int col_ = (CB) * NCHUNK + j_ * 16 + lane15;                          \
        _Pragma("unroll")                                                     \
        for (int m_ = 0; m_ < 2; ++m_)                                        \
            _Pragma("unroll")                                                 \
            for (int r_ = 0; r_ < 4; ++r_) {                                  \
                float s_ = fmaf(-2.0f, A[m_][j_][r_], CC4[j_]);               \
                s_ = fmaxf(s_, 0.25f);                                        \
                unsigned up_ = (__float_as_uint(s_) & 0xFFFFFC00u) | (unsigned)col_; \
                unsigned a_  = p1[m_][r_];                                    \
                unsigned lo_ = a_ < up_ ? a_ : up_;                           \
                unsigned hi_ = a_ < up_ ? up_ : a_;                           \
                p1[m_][r_] = lo_;                                             \
                p2[m_][r_] = p2[m_][r_] < hi_ ? p2[m_][r_] : hi_;             \
            }                                                                 \
    }

#define LOADCC(DST, C)                                                        \
    {                                                                         \
        float4 ccv_ = *(const float4*)&ccL[(((C) << 4) + lane15) << 2];       \
        DST[0] = ccv_.x; DST[1] = ccv_.y; DST[2] = ccv_.z; DST[3] = ccv_.w;   \
    }

__global__ __launch_bounds__(256, 2) void vq_gemm(const float* __restrict__ x,
                                                  const _Float16* __restrict__ ch,
                                                  const float* __restrict__ cc,
                                                  int* __restrict__ idx,
                                                  int* __restrict__ cnt,
                                                  int* __restrict__ wl) {
    __shared__ _Float16 bs[2][NCHUNK * DIM];   // 2 x 16 KB double buffer
    __shared__ float ccL[NCODES];              // 4 KB, packed [c][lane15][j]

    const int t      = threadIdx.x;
    const int w      = t >> 6;
    const int L      = t & 63;
    const int lane15 = L & 15;
    const int quad   = L >> 4;
    const int rowbase = blockIdx.x * MTILE + w * 32;

    stage_chunk(ch, bs[0], 0, w, quad, lane15);

    // cc+4 into LDS once, float4-packed: ccL[(c*16+l)*4+j] = cc[c*64+j*16+l]+4.
#pragma unroll
    for (int i = 0; i < 4; ++i) {
        int e = t + 256 * i;            // 0..1023 (dest index)
        int c = e >> 6, rem = e & 63;
        int l = rem >> 2, j = rem & 3;
        ccL[e] = cc[c * 64 + j * 16 + l] + 4.0f;
    }

    // A fragments from global x (f32 -> fp16), persistent across chunks.
    half8 af[2][4];
#pragma unroll
    for (int m = 0; m < 2; ++m) {
#pragma unroll
        for (int ks = 0; ks < 4; ++ks) {
            const float* src = x + (size_t)(rowbase + m * 16 + lane15) * DIM
                                 + ks * 32 + quad * 8;
            float4 f0 = *(const float4*)src;
            float4 f1 = *(const float4*)(src + 4);
            half8 h;
            h[0] = (_Float16)f0.x; h[1] = (_Float16)f0.y;
            h[2] = (_Float16)f0.z; h[3] = (_Float16)f0.w;
            h[4] = (_Float16)f1.x; h[5] = (_Float16)f1.y;
            h[6] = (_Float16)f1.z; h[7] = (_Float16)f1.w;
            af[m][ks] = h;
        }
    }

    int roff[4];
#pragma unroll
    for (int ks = 0; ks < 4; ++ks)
        roff[ks] = lane15 * DIM + ((((ks << 2) + quad) ^ (lane15 & 7)) << 3);

    unsigned p1[2][4], p2[2][4];
#pragma unroll
    for (int m = 0; m < 2; ++m)
#pragma unroll
        for (int r = 0; r < 4; ++r) { p1[m][r] = 0xFFFFFFFFu; p2[m][r] = 0xFFFFFFFFu; }

    __syncthreads();   // chunk-0 DMA + ccL writes resident

    f32x4 accA[2][4], accB[2][4];
    float cc4A[4], cc4B[4];

    // Chunk 0 -> accA (no deferred epilogue yet).
    stage_chunk(ch, bs[1], 1, w, quad, lane15);
    LOADCC(cc4A, 0);
    ZACC(accA);
    CHAIN(bs[0], accA);
    __syncthreads();

    // Chunks 1..14, two per iteration; epilogue runs one chunk behind,
    // inside the SAME barrier interval as the next chunk's MFMA chain.
    for (int c = 1; c < 15; c += 2) {
        // odd chunk c -> accB from bs[1]; epilogue chunk c-1 (accA)
        stage_chunk(ch, bs[0], c + 1, w, quad, lane15);
        LOADCC(cc4B, c);
        ZACC(accB);
        CHAIN(bs[1], accB);
        EPI(accA, c - 1, cc4A);
        __syncthreads();

        // even chunk c+1 -> accA from bs[0]; epilogue chunk c (accB)
        stage_chunk(ch, bs[1], c + 2, w, quad, lane15);
        LOADCC(cc4A, c + 1);
        ZACC(accA);
        CHAIN(bs[0], accA);
        EPI(accB, c, cc4B);
        __syncthreads();
    }

    // Chunk 15 -> accB from bs[1] (staged in the last loop iteration);
    // epilogue 14 (accA) overlaps, then epilogue 15.
    LOADCC(cc4B, 15);
    ZACC(accB);
    CHAIN(bs[1], accB);
    EPI(accA, 14, cc4A);
    EPI(accB, 15, cc4B);

    // Cross-lane top-2 merge over the 16 col-lanes.
#pragma unroll
    for (int m = 0; m < 2; ++m)
#pragma unroll
        for (int r = 0; r < 4; ++r) {
            unsigned a1 = p1[m][r], a2 = p2[m][r];
#pragma unroll
            for (int mask = 1; mask <= 8; mask <<= 1) {
                unsigned b1 = (unsigned)__shfl_xor((int)a1, mask, 64);
                unsigned b2 = (unsigned)__shfl_xor((int)a2, mask, 64);
                unsigned n1 = a1 < b1 ? a1 : b1;
                unsigned hi = a1 < b1 ? b1 : a1;
                unsigned mn = a2 < b2 ? a2 : b2;
                unsigned n2 = hi < mn ? hi : mn;
                a1 = n1; a2 = n2;
            }
            if (lane15 == 0) {
                int row = rowbase + m * 16 + quad * 4 + r;
                idx[row] = (int)(a1 & 0x3FFu);
                float s1 = __uint_as_float(a1 & 0xFFFFFC00u);
                float s2 = __uint_as_float(a2 & 0xFFFFFC00u);
                if (s2 - s1 < M_TEST) {
                    int slot = atomicAdd(cnt, 1);
                    if (slot < WL_CAP) wl[slot] = row;
                }
            }
        }
}

// ---------------------------------------------------------------------------
// Phase 2 v3: np-exact rescoring (internals unchanged; grid 1024 so every
// block handles <=1 item for any count <= WL_CAP -> no 2x makespan imbalance).
// Block item = 64 flagged rows x 256 codes; thread tile 4x4; atomicMin merge.
// ---------------------------------------------------------------------------
__global__ __launch_bounds__(256, 2) void vq_exact(const float* __restrict__ x,
                                                   const float* __restrict__ cbT,
                                                   const float* __restrict__ cc,
                                                   const int* __restrict__ cnt,
                                                   const int* __restrict__ wl,
                                                   unsigned long long* __restrict__ bst) {
    __shared__ float xsS[GR * CSTR];     // 64 staged x-rows
    __shared__ float cbS[64 * CSTR];     // 64-code chunk
    __shared__ float xxS[GR];

    const int t  = threadIdx.x;
    const int r4 = t >> 4;      // row group 0..15 (rows 4*r4 .. 4*r4+3)
    const int q  = t & 15;      // code residue 0..15

    int count = *cnt;
    if (count > WL_CAP) count = WL_CAP;
    const int ngrp   = (count + GR - 1) / GR;
    const int nitems = ngrp * 4;

    for (int it = blockIdx.x; it < nitems; it += gridDim.x) {
        const int grp = it >> 2;        // row group (consecutive blocks share rows)
        const int cq  = it & 3;         // code quarter

        __syncthreads();   // previous item's xsS readers done
#pragma unroll
        for (int j = 0; j < 8; ++j) {
            int e  = t + 256 * j;       // float4 index 0..2047
            int rr = e >> 5, k4 = e & 31;
            int sl = grp * GR + rr;
            sl = sl < count ? sl : count - 1;   // clamp: dup rows benign (guarded at merge)
            int rw = wl[sl];
            float4 v = ((const float4*)x)[(size_t)rw * 32 + k4];
            *(float4*)&xsS[rr * CSTR + k4 * 4] = v;
        }
        __syncthreads();

        // xx once per row: numpy pairwise sum, n=128 block, 8 accumulators
        // (verified form), computed by wave 0 (one thread per row).
        if (t < GR) {
            const float* xs = &xsS[t * CSTR];
            float r0 = sqf(xs[0]), r1 = sqf(xs[1]), r2 = sqf(xs[2]), r3 = sqf(xs[3]);
            float r4_ = sqf(xs[4]), r5 = sqf(xs[5]), r6 = sqf(xs[6]), r7 = sqf(xs[7]);
#pragma unroll
            for (int k = 8; k < DIM; k += 8) {
                r0 = r0 + sqf(xs[k + 0]); r1 = r1 + sqf(xs[k + 1]);
                r2 = r2 + sqf(xs[k + 2]); r3 = r3 + sqf(xs[k + 3]);
                r4_ = r4_ + sqf(xs[k + 4]); r5 = r5 + sqf(xs[k + 5]);
                r6 = r6 + sqf(xs[k + 6]); r7 = r7 + sqf(xs[k + 7]);
            }
            xxS[t] = ((r0 + r1) + (r2 + r3)) + ((r4_ + r5) + (r6 + r7));
        }
        __syncthreads();

        float xxv[4];
#pragma unroll
        for (int i = 0; i < 4; ++i) xxv[i] = xxS[r4 * 4 + i];

        unsigned long long best[4];
#pragma unroll
        for (int i = 0; i < 4; ++i) best[i] = 0xFFFFFFFFFFFFFFFFull;

        for (int ch = 0; ch < 4; ++ch) {
            const int nb = cq * 256 + ch * 64;      // global code base of chunk
            __syncthreads();   // previous chunk's cbS readers done
#pragma unroll
            for (int j = 0; j < 8; ++j) {
                int e  = t + 256 * j;               // float4 index 0..2047
                int ci = e >> 5, k4 = e & 31;
                float4 v = ((const float4*)cbT)[(size_t)(nb + ci) * 32 + k4];
                *(float4*)&cbS[ci * CSTR + k4 * 4] = v;
            }
            __syncthreads();

            float a[4][4];
#pragma unroll
            for (int i = 0; i < 4; ++i)
#pragma unroll
                for (int j = 0; j < 4; ++j) a[i][j] = 0.f;

#pragma unroll 4
            for (int k4 = 0; k4 < 32; ++k4) {
                float4 xv[4], cv[4];
#pragma unroll
                for (int i = 0; i < 4; ++i)
                    xv[i] = *(const float4*)&xsS[(r4 * 4 + i) * CSTR + k4 * 4];
#pragma unroll
                for (int j = 0; j < 4; ++j)
                    cv[j] = *(const float4*)&cbS[(q + 16 * j) * CSTR + k4 * 4];
#pragma unroll
                for (int i = 0; i < 4; ++i)
#pragma unroll
                    for (int j = 0; j < 4; ++j) {
                        float acc = a[i][j];
                        acc = fmaf(cv[j].x, xv[i].x, acc);
                        acc = fmaf(cv[j].y, xv[i].y, acc);
                        acc = fmaf(cv[j].z, xv[i].z, acc);
                        acc = fmaf(cv[j].w, xv[i].w, acc);
                        a[i][j] = acc;
                    }
            }

#pragma unroll
            for (int j = 0; j < 4; ++j) {
                int n = nb + q + 16 * j;
                float ccn = cc[n];
#pragma unroll
                for (int i = 0; i < 4; ++i) {
                    float tt = xxv[i] + ccn;
                    float d  = tt - (a[i][j] + a[i][j]);
                    unsigned u  = __float_as_uint(d);
                    unsigned mk = (unsigned)(((int)u) >> 31);
                    unsigned f  = u ^ (mk | 0x80000000u);
                    unsigned long long key = ((unsigned long long)f << 32) | (unsigned)n;
                    best[i] = key < best[i] ? key : best[i];
                }
            }
        }

#pragma unroll
        for (int i = 0; i < 4; ++i) {
            unsigned long long b = best[i];
#pragma unroll
            for (int mask = 1; mask <= 8; mask <<= 1) {
                unsigned long long o =
                    (unsigned long long)__shfl_xor((long long)b, mask, 64);
                b = o < b ? o : b;
            }
            if (q == 0) {
                int sl = grp * GR + r4 * 4 + i;
                if (sl < count) atomicMin(&bst[sl], b);
            }
        }
    }
}

// ---------------------------------------------------------------------------
// Phase 2b: write merged winners into idx.
// ---------------------------------------------------------------------------
__global__ void vq_fix(const int* __restrict__ cnt,
                       const int* __restrict__ wl,
                       const unsigned long long* __restrict__ bst,
                       int* __restrict__ idx) {
    int count = *cnt;
    if (count > WL_CAP) count = WL_CAP;
    for (int s = blockIdx.x * 256 + threadIdx.x; s < count; s += gridDim.x * 256)
        idx[wl[s]] = (int)(bst[s] & 0xFFFFFFFFull);
}

// ---------------------------------------------------------------------------
// Phase 3: out = q (codebook column idx[row]); |q - (x + fl(q-x))| <= 4e-7,
// well under the 1e-3 threshold, and skips the 64 MB x read.
// ---------------------------------------------------------------------------
__global__ void vq_out(const float* __restrict__ cbT,
                       const int* __restrict__ idx,
                       float* __restrict__ out) {
    size_t e = (size_t)blockIdx.x * 256 + threadIdx.x;   // float4 index
    int row = (int)(e >> 5);
    int k4  = (int)(e & 31);
    ((float4*)out)[e] = ((const float4*)cbT)[(size_t)idx[row] * 32 + k4];
}

// ---------------------------------------------------------------------------
extern "C" void kernel_launch(void* const* d_in, const int* in_sizes, int n_in,
                              void* d_out, int out_size, void* d_ws, size_t ws_size,
                              hipStream_t stream) {
    const float* x  = (const float*)d_in[0];   // [131072,128] f32
    const float* cb = (const float*)d_in[1];   // [128,1024] f32
    float* out = (float*)d_out;

    char* p = (char*)d_ws;
    float*    cbT = (float*)p;               p += NCODES * DIM * sizeof(float);
    _Float16* ch  = (_Float16*)p;            p += NCODES * DIM * sizeof(_Float16);
    float*    cc  = (float*)p;               p += NCODES * sizeof(float);
    int*      idx = (int*)p;                 p += M_ROWS * sizeof(int);
    int*      cnt = (int*)p;                 p += 16 * sizeof(int);
    int*      wl  = (int*)p;                 p += WL_CAP * sizeof(int);
    unsigned long long* bst = (unsigned long long*)p;

    vq_prep<<<580, 256, 0, stream>>>(cb, cbT, ch, cc, cnt, bst);
    vq_gemm<<<M_ROWS / MTILE, 256, 0, stream>>>(x, ch, cc, idx, cnt, wl);
    vq_exact<<<1024, 256, 0, stream>>>(x, cbT, cc, cnt, wl, bst);
    vq_fix<<<64, 256, 0, stream>>>(cnt, wl, bst, idx);
    vq_out<<<(M_ROWS * (DIM / 4)) / 256, 256, 0, stream>>>(cbT, idx, out);
}

// Round 7
// 187.906 us; speedup vs baseline: 1.0623x; 1.0436x over previous
//
#include <hip/hip_runtime.h>
#include <math.h>

typedef _Float16 half8 __attribute__((ext_vector_type(8)));
typedef float    f32x4 __attribute__((ext_vector_type(4)));

#define DIM     128
#define NCODES  1024
#define M_ROWS  (32*64*64)   // 131072
#define MTILE   128          // rows per block in phase 1 (4 waves x 32 rows)
#define NCHUNK  64           // codes per LDS chunk in phase 1
#define M_TEST  3.0e-3f      // flag margin (quantized-score gap)
#define WL_CAP  16384
#define GR      64           // flagged rows per vq_exact block
#define CSTR    132          // f32 LDS stride (528 B, 16B aligned; worst alias 2-way = free)

// fl32(v*v), immune to FMA contraction (f64 product exact, one rounding).
__device__ __forceinline__ float sqf(float v) {
    return (float)((double)v * (double)v);
}

// ---------------------------------------------------------------------------
// Prep: blocks 0..511 transpose cb->cbT (f32) and ch (fp16), one elem/thread.
// Blocks 512..515: cc[n] = np axis-0 sequential sum of rounded squares.
// Blocks 516..579: init bst[] (per-flagged-row best key) to all-ones.
// ---------------------------------------------------------------------------
__global__ void vq_prep(const float* __restrict__ cb,
                        float* __restrict__ cbT,
                        _Float16* __restrict__ ch,
                        float* __restrict__ cc,
                        int* __restrict__ cnt,
                        unsigned long long* __restrict__ bst) {
    const int b = blockIdx.x;
    if (b < 512) {
        int e = b * 256 + threadIdx.x;      // 0..131071
        int n = e & 1023, k = e >> 10;
        float v = cb[k * NCODES + n];       // coalesced in n
        cbT[n * DIM + k] = v;
        ch[n * DIM + k]  = (_Float16)v;
    } else if (b < 516) {
        int n = (b - 512) * 256 + threadIdx.x;   // 0..1023
        float acc = 0.f;
        for (int k = 0; k < DIM; ++k)
            acc = acc + sqf(cb[k * NCODES + n]); // np axis-0 order
        cc[n] = acc;
        if (n == 0) *cnt = 0;
    } else {
        int s = (b - 516) * 256 + threadIdx.x;   // 0..16383
        bst[s] = 0xFFFFFFFFFFFFFFFFull;
    }
}

// ---------------------------------------------------------------------------
// Phase 1 v7: fp16 MFMA scoring, fused top-2 argmin, COUNTED-VMCNT PIPELINE.
//  All r0-r6 variants pinned at 63-76us with every pipe <=46% busy: the
//  2-phase {stage -> compute -> vmcnt(0)-drain at __syncthreads} structure
//  has a fixed per-interval drain overhead (the DMA issued at the top of an
//  interval is drained at its bottom barrier). Fix (T3/T4): 3 LDS buffers,
//  stage(c+2) issued AFTER the interval-c barrier (WAR-safe: readers of that
//  buffer finished interval c-1), raw s_barrier + inline s_waitcnt vmcnt(4)
//  (leave chunk c+1's 4 DMA loads in flight; in-order retirement => chunk
//  c's loads complete). No other VMEM exists in the loop (cc is LDS).
// Per-(row,code) arithmetic bit-identical (same fp16 inputs, MFMA k-order,
// score formula incl. +4.0f rounding, pack, top-2 update order per code).
// ---------------------------------------------------------------------------
__device__ __forceinline__ void stage_chunk(const _Float16* __restrict__ ch,
                                            _Float16* lds,
                                            int chunk, int w, int quad, int lane15) {
#pragma unroll
    for (int i = 0; i < 4; ++i) {
        int r = (w << 4) + (i << 2) + quad;          // code row 0..63 of chunk
        const _Float16* g = ch + (size_t)(chunk * NCHUNK + r) * DIM
                               + ((lane15 ^ (r & 7)) << 3);
        __builtin_amdgcn_global_load_lds(
            (const __attribute__((address_space(1))) void*)g,
            (__attribute__((address_space(3))) void*)(lds + (w << 11) + (i << 9)),
            16, 0, 0);
    }
}

__global__ __launch_bounds__(256, 2) void vq_gemm(const float* __restrict__ x,
                                                  const _Float16* __restrict__ ch,
                                                  const float* __restrict__ cc,
                                                  int* __restrict__ idx,
                                                  int* __restrict__ cnt,
                                                  int* __restrict__ wl) {
    __shared__ _Float16 bs[3][NCHUNK * DIM];   // 3 x 16 KB rotating buffers
    __shared__ float ccL[NCODES];              // 4 KB, packed [c][lane15][j]

    const int t      = threadIdx.x;
    const int w      = t >> 6;
    const int L      = t & 63;
    const int lane15 = L & 15;
    const int quad   = L >> 4;
    const int rowbase = blockIdx.x * MTILE + w * 32;

    stage_chunk(ch, bs[0], 0, w, quad, lane15);
    stage_chunk(ch, bs[1], 1, w, quad, lane15);

    // cc+4 into LDS once, float4-packed: ccL[(c*16+l)*4+j] = cc[c*64+j*16+l]+4.
#pragma unroll
    for (int i = 0; i < 4; ++i) {
        int e = t + 256 * i;            // 0..1023 (dest index)
        int c = e >> 6, rem = e & 63;
        int l = rem >> 2, j = rem & 3;
        ccL[e] = cc[c * 64 + j * 16 + l] + 4.0f;
    }

    // A fragments from global x (f32 -> fp16), persistent across chunks.
    half8 af[2][4];
#pragma unroll
    for (int m = 0; m < 2; ++m) {
#pragma unroll
        for (int ks = 0; ks < 4; ++ks) {
            const float* src = x + (size_t)(rowbase + m * 16 + lane15) * DIM
                                 + ks * 32 + quad * 8;
            float4 f0 = *(const float4*)src;
            float4 f1 = *(const float4*)(src + 4);
            half8 h;
            h[0] = (_Float16)f0.x; h[1] = (_Float16)f0.y;
            h[2] = (_Float16)f0.z; h[3] = (_Float16)f0.w;
            h[4] = (_Float16)f1.x; h[5] = (_Float16)f1.y;
            h[6] = (_Float16)f1.z; h[7] = (_Float16)f1.w;
            af[m][ks] = h;
        }
    }

    int roff[4];
#pragma unroll
    for (int ks = 0; ks < 4; ++ks)
        roff[ks] = lane15 * DIM + ((((ks << 2) + quad) ^ (lane15 & 7)) << 3);

    unsigned p1[2][4], p2[2][4];
#pragma unroll
    for (int m = 0; m < 2; ++m)
#pragma unroll
        for (int r = 0; r < 4; ++r) { p1[m][r] = 0xFFFFFFFFu; p2[m][r] = 0xFFFFFFFFu; }

    const _Float16* bp0 = bs[0];   // chunk c
    const _Float16* bp1 = bs[1];   // chunk c+1 (in flight)
    _Float16*       bp2 = bs[2];   // stage target for chunk c+2

#pragma unroll 1
    for (int c = 0; c < 16; ++c) {
        // Wait: chunk c's 4 DMA loads complete (newest 4 = chunk c+1 may fly);
        // lgkmcnt(0) covers the prologue ccL ds_writes at c==0 (free later).
        if (c < 15)
            asm volatile("s_waitcnt vmcnt(4) lgkmcnt(0)" ::: "memory");
        else
            asm volatile("s_waitcnt vmcnt(0) lgkmcnt(0)" ::: "memory");
        __builtin_amdgcn_s_barrier();          // raw: no compiler vmcnt(0) drain
        __builtin_amdgcn_sched_barrier(0);

        // Issue chunk c+2 into the buffer all waves finished reading in c-1.
        if (c < 14)
            stage_chunk(ch, bp2, c + 2, w, quad, lane15);

        float4 ccv = *(const float4*)&ccL[((c << 4) + lane15) << 2];
        float cc4[4] = {ccv.x, ccv.y, ccv.z, ccv.w};

        f32x4 acc[2][4];
#pragma unroll
        for (int m = 0; m < 2; ++m)
#pragma unroll
            for (int j = 0; j < 4; ++j) {
                f32x4 z = {0.f, 0.f, 0.f, 0.f};
                acc[m][j] = z;
            }

#pragma unroll
        for (int ks = 0; ks < 4; ++ks) {
            half8 bf[4];
#pragma unroll
            for (int j = 0; j < 4; ++j)
                bf[j] = *(const half8*)(bp0 + (j << 11) + roff[ks]);
#pragma unroll
            for (int j = 0; j < 4; ++j)
#pragma unroll
                for (int m = 0; m < 2; ++m)
                    acc[m][j] = __builtin_amdgcn_mfma_f32_16x16x32_f16(af[m][ks], bf[j], acc[m][j], 0, 0, 0);
        }

#pragma unroll
        for (int j = 0; j < 4; ++j) {
            int col = c * NCHUNK + j * 16 + lane15;
#pragma unroll
            for (int m = 0; m < 2; ++m)
#pragma unroll
                for (int r = 0; r < 4; ++r) {
                    float s = fmaf(-2.0f, acc[m][j][r], cc4[j]);
                    s = fmaxf(s, 0.25f);
                    unsigned up = (__float_as_uint(s) & 0xFFFFFC00u) | (unsigned)col;
                    unsigned a  = p1[m][r];
                    unsigned lo = a < up ? a : up;
                    unsigned hi = a < up ? up : a;
                    p1[m][r] = lo;
                    p2[m][r] = p2[m][r] < hi ? p2[m][r] : hi;
                }
        }

        // Rotate buffers: c+1 becomes current; freed buffer is next stage tgt.
        _Float16* tmp = (_Float16*)bp0;
        bp0 = bp1; bp1 = bp2; bp2 = tmp;
    }

    // Cross-lane top-2 merge over the 16 col-lanes.
#pragma unroll
    for (int m = 0; m < 2; ++m)
#pragma unroll
        for (int r = 0; r < 4; ++r) {
            unsigned a1 = p1[m][r], a2 = p2[m][r];
#pragma unroll
            for (int mask = 1; mask <= 8; mask <<= 1) {
                unsigned b1 = (unsigned)__shfl_xor((int)a1, mask, 64);
                unsigned b2 = (unsigned)__shfl_xor((int)a2, mask, 64);
                unsigned n1 = a1 < b1 ? a1 : b1;
                unsigned hi = a1 < b1 ? b1 : a1;
                unsigned mn = a2 < b2 ? a2 : b2;
                unsigned n2 = hi < mn ? hi : mn;
                a1 = n1; a2 = n2;
            }
            if (lane15 == 0) {
                int row = rowbase + m * 16 + quad * 4 + r;
                idx[row] = (int)(a1 & 0x3FFu);
                float s1 = __uint_as_float(a1 & 0xFFFFFC00u);
                float s2 = __uint_as_float(a2 & 0xFFFFFC00u);
                if (s2 - s1 < M_TEST) {
                    int slot = atomicAdd(cnt, 1);
                    if (slot < WL_CAP) wl[slot] = row;
                }
            }
        }
}

// ---------------------------------------------------------------------------
// Phase 2 v3: np-exact rescoring (unchanged; grid 1024 -> <=1 item/block).
// Block item = 64 flagged rows x 256 codes; thread tile 4x4; atomicMin merge.
// ---------------------------------------------------------------------------
__global__ __launch_bounds__(256, 2) void vq_exact(const float* __restrict__ x,
                                                   const float* __restrict__ cbT,
                                                   const float* __restrict__ cc,
                                                   const int* __restrict__ cnt,
                                                   const int* __restrict__ wl,
                                                   unsigned long long* __restrict__ bst) {
    __shared__ float xsS[GR * CSTR];     // 64 staged x-rows
    __shared__ float cbS[64 * CSTR];     // 64-code chunk
    __shared__ float xxS[GR];

    const int t  = threadIdx.x;
    const int r4 = t >> 4;      // row group 0..15 (rows 4*r4 .. 4*r4+3)
    const int q  = t & 15;      // code residue 0..15

    int count = *cnt;
    if (count > WL_CAP) count = WL_CAP;
    const int ngrp   = (count + GR - 1) / GR;
    const int nitems = ngrp * 4;

    for (int it = blockIdx.x; it < nitems; it += gridDim.x) {
        const int grp = it >> 2;        // row group (consecutive blocks share rows)
        const int cq  = it & 3;         // code quarter

        __syncthreads();   // previous item's xsS readers done
#pragma unroll
        for (int j = 0; j < 8; ++j) {
            int e  = t + 256 * j;       // float4 index 0..2047
            int rr = e >> 5, k4 = e & 31;
            int sl = grp * GR + rr;
            sl = sl < count ? sl : count - 1;   // clamp: dup rows benign (guarded at merge)
            int rw = wl[sl];
            float4 v = ((const float4*)x)[(size_t)rw * 32 + k4];
            *(float4*)&xsS[rr * CSTR + k4 * 4] = v;
        }
        __syncthreads();

        // xx once per row: numpy pairwise sum, n=128 block, 8 accumulators
        // (verified form), computed by wave 0 (one thread per row).
        if (t < GR) {
            const float* xs = &xsS[t * CSTR];
            float r0 = sqf(xs[0]), r1 = sqf(xs[1]), r2 = sqf(xs[2]), r3 = sqf(xs[3]);
            float r4_ = sqf(xs[4]), r5 = sqf(xs[5]), r6 = sqf(xs[6]), r7 = sqf(xs[7]);
#pragma unroll
            for (int k = 8; k < DIM; k += 8) {
                r0 = r0 + sqf(xs[k + 0]); r1 = r1 + sqf(xs[k + 1]);
                r2 = r2 + sqf(xs[k + 2]); r3 = r3 + sqf(xs[k + 3]);
                r4_ = r4_ + sqf(xs[k + 4]); r5 = r5 + sqf(xs[k + 5]);
                r6 = r6 + sqf(xs[k + 6]); r7 = r7 + sqf(xs[k + 7]);
            }
            xxS[t] = ((r0 + r1) + (r2 + r3)) + ((r4_ + r5) + (r6 + r7));
        }
        __syncthreads();

        float xxv[4];
#pragma unroll
        for (int i = 0; i < 4; ++i) xxv[i] = xxS[r4 * 4 + i];

        unsigned long long best[4];
#pragma unroll
        for (int i = 0; i < 4; ++i) best[i] = 0xFFFFFFFFFFFFFFFFull;

        for (int ch = 0; ch < 4; ++ch) {
            const int nb = cq * 256 + ch * 64;      // global code base of chunk
            __syncthreads();   // previous chunk's cbS readers done
#pragma unroll
            for (int j = 0; j < 8; ++j) {
                int e  = t + 256 * j;               // float4 index 0..2047
                int ci = e >> 5, k4 = e & 31;
                float4 v = ((const float4*)cbT)[(size_t)(nb + ci) * 32 + k4];
                *(float4*)&cbS[ci * CSTR + k4 * 4] = v;
            }
            __syncthreads();

            float a[4][4];
#pragma unroll
            for (int i = 0; i < 4; ++i)
#pragma unroll
                for (int j = 0; j < 4; ++j) a[i][j] = 0.f;

#pragma unroll 4
            for (int k4 = 0; k4 < 32; ++k4) {
                float4 xv[4], cv[4];
#pragma unroll
                for (int i = 0; i < 4; ++i)
                    xv[i] = *(const float4*)&xsS[(r4 * 4 + i) * CSTR + k4 * 4];
#pragma unroll
                for (int j = 0; j < 4; ++j)
                    cv[j] = *(const float4*)&cbS[(q + 16 * j) * CSTR + k4 * 4];
#pragma unroll
                for (int i = 0; i < 4; ++i)
#pragma unroll
                    for (int j = 0; j < 4; ++j) {
                        float acc = a[i][j];
                        acc = fmaf(cv[j].x, xv[i].x, acc);
                        acc = fmaf(cv[j].y, xv[i].y, acc);
                        acc = fmaf(cv[j].z, xv[i].z, acc);
                        acc = fmaf(cv[j].w, xv[i].w, acc);
                        a[i][j] = acc;
                    }
            }

#pragma unroll
            for (int j = 0; j < 4; ++j) {
                int n = nb + q + 16 * j;
                float ccn = cc[n];
#pragma unroll
                for (int i = 0; i < 4; ++i) {
                    float tt = xxv[i] + ccn;
                    float d  = tt - (a[i][j] + a[i][j]);
                    unsigned u  = __float_as_uint(d);
                    unsigned mk = (unsigned)(((int)u) >> 31);
                    unsigned f  = u ^ (mk | 0x80000000u);
                    unsigned long long key = ((unsigned long long)f << 32) | (unsigned)n;
                    best[i] = key < best[i] ? key : best[i];
                }
            }
        }

#pragma unroll
        for (int i = 0; i < 4; ++i) {
            unsigned long long b = best[i];
#pragma unroll
            for (int mask = 1; mask <= 8; mask <<= 1) {
                unsigned long long o =
                    (unsigned long long)__shfl_xor((long long)b, mask, 64);
                b = o < b ? o : b;
            }
            if (q == 0) {
                int sl = grp * GR + r4 * 4 + i;
                if (sl < count) atomicMin(&bst[sl], b);
            }
        }
    }
}

// ---------------------------------------------------------------------------
// Phase 2b: write merged winners into idx.
// ---------------------------------------------------------------------------
__global__ void vq_fix(const int* __restrict__ cnt,
                       const int* __restrict__ wl,
                       const unsigned long long* __restrict__ bst,
                       int* __restrict__ idx) {
    int count = *cnt;
    if (count > WL_CAP) count = WL_CAP;
    for (int s = blockIdx.x * 256 + threadIdx.x; s < count; s += gridDim.x * 256)
        idx[wl[s]] = (int)(bst[s] & 0xFFFFFFFFull);
}

// ---------------------------------------------------------------------------
// Phase 3: out = q (codebook column idx[row]); |q - (x + fl(q-x))| <= 4e-7,
// well under the 1e-3 threshold, and skips the 64 MB x read.
// ---------------------------------------------------------------------------
__global__ void vq_out(const float* __restrict__ cbT,
                       const int* __restrict__ idx,
                       float* __restrict__ out) {
    size_t e = (size_t)blockIdx.x * 256 + threadIdx.x;   // float4 index
    int row = (int)(e >> 5);
    int k4  = (int)(e & 31);
    ((float4*)out)[e] = ((const float4*)cbT)[(size_t)idx[row] * 32 + k4];
}

// ---------------------------------------------------------------------------
extern "C" void kernel_launch(void* const* d_in, const int* in_sizes, int n_in,
                              void* d_out, int out_size, void* d_ws, size_t ws_size,
                              hipStream_t stream) {
    const float* x  = (const float*)d_in[0];   // [131072,128] f32
    const float* cb = (const float*)d_in[1];   // [128,1024] f32
    float* out = (float*)d_out;

    char* p = (char*)d_ws;
    float*    cbT = (float*)p;               p += NCODES * DIM * sizeof(float);
    _Float16* ch  = (_Float16*)p;            p += NCODES * DIM * sizeof(_Float16);
    float*    cc  = (float*)p;               p += NCODES * sizeof(float);
    int*      idx = (int*)p;                 p += M_ROWS * sizeof(int);
    int*      cnt = (int*)p;                 p += 16 * sizeof(int);
    int*      wl  = (int*)p;                 p += WL_CAP * sizeof(int);
    unsigned long long* bst = (unsigned long long*)p;

    vq_prep<<<580, 256, 0, stream>>>(cb, cbT, ch, cc, cnt, bst);
    vq_gemm<<<M_ROWS / MTILE, 256, 0, stream>>>(x, ch, cc, idx, cnt, wl);
    vq_exact<<<1024, 256, 0, stream>>>(x, cbT, cc, cnt, wl, bst);
    vq_fix<<<64, 256, 0, stream>>>(cnt, wl, bst, idx);
    vq_out<<<(M_ROWS * (DIM / 4)) / 256, 256, 0, stream>>>(cbT, idx, out);
}